// Round 1
// baseline (1992.636 us; speedup 1.0000x reference)
//
#include <hip/hip_runtime.h>

#define DEV __device__ __forceinline__

typedef _Float16 half8 __attribute__((ext_vector_type(8)));
typedef float f32x4 __attribute__((ext_vector_type(4)));

DEV void gload_lds16(const void* g, void* l) {
  __builtin_amdgcn_global_load_lds(
      (const __attribute__((address_space(1))) void*)g,
      (__attribute__((address_space(3))) void*)l, 16, 0, 0);
}

DEV float sigmoidf_(float x) { return 1.f / (1.f + __expf(-x)); }
DEV float tanh_fast(float x) { return 1.f - 2.f / (__expf(2.f * x) + 1.f); }

struct GArgs {
  const _Float16* A;   // f16 A operand (row-major, lda elements per row)
  const float* Af;     // f32 A operand (for convert-on-stage path)
  const _Float16* BT;  // weights, transposed [N][K], row stride = K
  long lda;
  int K;
  int t;
  const float* bias;
  const float* bias2;
  _Float16* cat;    // [4096][1536] = [s' | x]
  _Float16* cat2;   // [4096][1536] = [r*s' | x]
  _Float16* u_h;    // [4096][1024]
  _Float16* state_h;// [4096][1024]
  float* out;       // [4096][12][512]
};

// 128x128 tile, BK=32, 4 waves (each 64x64 = 4x4 frags of 16x16x32 f16 MFMA).
// LDS layout: tile stored as 512 slots of 16B; logical (row m, k-group g) lives
// at slot m*4 + (g ^ ((m>>1)&3)) -- the XOR spreads ds_read_b128 across bank
// groups (2-way max = free) while staging stays linear for global_load_lds
// (the inverse permutation is applied to the per-lane GLOBAL source address).
template <int EPI, bool AF32>
__global__ __launch_bounds__(256) void gemm_k(GArgs g) {
  __shared__ __align__(16) _Float16 As[4096];
  __shared__ __align__(16) _Float16 Bs[4096];
  const int tid = threadIdx.x;
  const int lane = tid & 63;
  const int wave = tid >> 6;
  const int bm = blockIdx.x * 128;
  const int bn = blockIdx.y * 128;
  const int wm = (wave >> 1) * 64;
  const int wn = (wave & 1) * 64;
  const int fr = lane & 15;  // frag row (A) / col (B)
  const int fg = lane >> 4;  // k-group 0..3 (8 halves each)

  // staging: wave w loads chunks w and w+4 (16 rows each); lane d covers
  // slot d of the chunk = (row m = chunk*16 + d>>2, stored slot g = d&3)
  const int d2 = lane >> 2, d3 = lane & 3;
  const int m0 = wave * 16 + d2;
  const int m1 = (wave + 4) * 16 + d2;
  const int g0 = d3 ^ ((m0 >> 1) & 3);  // logical k-group fetched into this slot
  const int g1 = d3 ^ ((m1 >> 1) & 3);

  const _Float16* gB0 = g.BT + (size_t)(bn + m0) * g.K + g0 * 8;
  const _Float16* gB1 = g.BT + (size_t)(bn + m1) * g.K + g1 * 8;
  const _Float16* gA0 = nullptr;
  const _Float16* gA1 = nullptr;
  if constexpr (!AF32) {
    gA0 = g.A + (size_t)(bm + m0) * g.lda + g0 * 8;
    gA1 = g.A + (size_t)(bm + m1) * g.lda + g1 * 8;
  }

  const f32x4 zv = {0.f, 0.f, 0.f, 0.f};
  f32x4 acc[4][4];
#pragma unroll
  for (int i = 0; i < 4; ++i)
#pragma unroll
    for (int j = 0; j < 4; ++j) acc[i][j] = zv;

  for (int k0 = 0; k0 < g.K; k0 += 32) {
    if (k0) __syncthreads();  // LDS reads of prev iter done before overwrite
    gload_lds16(gB0, Bs + wave * 512);
    gload_lds16(gB1, Bs + (wave + 4) * 512);
    gB0 += 32;
    gB1 += 32;
    if constexpr (!AF32) {
      gload_lds16(gA0, As + wave * 512);
      gload_lds16(gA1, As + (wave + 4) * 512);
      gA0 += 32;
      gA1 += 32;
    } else {
      // f32 -> f16 convert-on-stage (td slice). 512 slots, 256 threads.
#pragma unroll
      for (int i = 0; i < 2; ++i) {
        int s = tid + i * 256;
        int m = s >> 2;
        int gg = (s & 3) ^ ((m >> 1) & 3);
        const float* p = g.Af + (size_t)(bm + m) * g.lda + k0 + gg * 8;
        float4 v0 = *(const float4*)p;
        float4 v1 = *(const float4*)(p + 4);
        half8 h;
        h[0] = (_Float16)v0.x; h[1] = (_Float16)v0.y;
        h[2] = (_Float16)v0.z; h[3] = (_Float16)v0.w;
        h[4] = (_Float16)v1.x; h[5] = (_Float16)v1.y;
        h[6] = (_Float16)v1.z; h[7] = (_Float16)v1.w;
        *(half8*)(As + s * 8) = h;
      }
    }
    __syncthreads();

    half8 af[4], bf[4];
#pragma unroll
    for (int i = 0; i < 4; ++i) {
      int am = wm + i * 16 + fr;
      af[i] = *(const half8*)(As + (size_t)(am * 4 + (fg ^ ((am >> 1) & 3))) * 8);
      int bb = wn + i * 16 + fr;
      bf[i] = *(const half8*)(Bs + (size_t)(bb * 4 + (fg ^ ((bb >> 1) & 3))) * 8);
    }
#pragma unroll
    for (int i = 0; i < 4; ++i)
#pragma unroll
      for (int j = 0; j < 4; ++j)
        acc[i][j] =
            __builtin_amdgcn_mfma_f32_16x16x32_f16(af[i], bf[j], acc[i][j], 0, 0, 0);
  }

  // C/D layout (gfx950, verified): col = lane&15, row = (lane>>4)*4 + reg
  const int row0 = bm + wm + fg * 4;
  const int col0 = bn + wn + fr;
#pragma unroll
  for (int i = 0; i < 4; ++i) {
#pragma unroll
    for (int j = 0; j < 4; ++j) {
      const int col = col0 + j * 16;
#pragma unroll
      for (int r = 0; r < 4; ++r) {
        const int row = row0 + i * 16 + r;
        float v = acc[i][j][r];
        if constexpr (EPI == 0) {  // x = z@Wz + bz -> x-part of cat, cat2
          _Float16 h = (_Float16)(v + g.bias[col]);
          g.cat[(size_t)row * 1536 + 1024 + col] = h;
          g.cat2[(size_t)row * 1536 + 1024 + col] = h;
        } else if constexpr (EPI == 1) {  // s' = exp(-relu(belta))*state
          float b = __expf(-fmaxf(0.f, v + g.bias[col]));
          float s = b * (float)g.state_h[(size_t)row * 1024 + col];
          g.cat[(size_t)row * 1536 + col] = (_Float16)s;
        } else if constexpr (EPI == 2) {  // u (cols<1024) | r*s' (cols>=1024)
          if (col < 1024) {
            g.u_h[(size_t)row * 1024 + col] =
                (_Float16)sigmoidf_(v + g.bias[col]);
          } else {
            int c = col - 1024;
            float rr = sigmoidf_(v + g.bias2[c]);
            float sp = (float)g.cat[(size_t)row * 1536 + c];
            g.cat2[(size_t)row * 1536 + c] = (_Float16)(rr * sp);
          }
        } else if constexpr (EPI == 3) {  // state = (1-u)s' + u*tanh(...)
          float ns = tanh_fast(v + g.bias[col]);
          float sp = (float)g.cat[(size_t)row * 1536 + col];
          float u = (float)g.u_h[(size_t)row * 1024 + col];
          g.state_h[(size_t)row * 1024 + col] =
              (_Float16)((1.f - u) * sp + u * ns);
        } else {  // out = state@Wout + bo -> d_out (f32) + next x (f16)
          float o = v + g.bias[col];
          g.out[((size_t)row * 12 + g.t) * 512 + col] = o;
          _Float16 h = (_Float16)o;
          g.cat[(size_t)row * 1536 + 1024 + col] = h;
          g.cat2[(size_t)row * 1536 + 1024 + col] = h;
        }
      }
    }
  }
}

// f32 [K][N] row-major -> f16 [N][K] (transposed) via 32x32 LDS tile
__global__ __launch_bounds__(256) void transpose_cvt(const float* __restrict__ src,
                                                     _Float16* __restrict__ dst,
                                                     int K, int N) {
  __shared__ float tile[32][33];
  const int nb = blockIdx.x * 32;
  const int kb = blockIdx.y * 32;
  const int tx = threadIdx.x & 31;
  const int ty = threadIdx.x >> 5;
#pragma unroll
  for (int i = ty; i < 32; i += 8)
    tile[i][tx] = src[(size_t)(kb + i) * N + nb + tx];
  __syncthreads();
#pragma unroll
  for (int i = ty; i < 32; i += 8)
    dst[(size_t)(nb + i) * K + kb + tx] = (_Float16)tile[tx][i];
}

__global__ __launch_bounds__(256) void cvt_f16(const float* __restrict__ src,
                                               _Float16* __restrict__ dst) {
  int i = blockIdx.x * blockDim.x + threadIdx.x;
  const float4* p = (const float4*)(src + (size_t)i * 8);
  float4 a = p[0], b = p[1];
  half8 h;
  h[0] = (_Float16)a.x; h[1] = (_Float16)a.y;
  h[2] = (_Float16)a.z; h[3] = (_Float16)a.w;
  h[4] = (_Float16)b.x; h[5] = (_Float16)b.y;
  h[6] = (_Float16)b.z; h[7] = (_Float16)b.w;
  *(half8*)(dst + (size_t)i * 8) = h;
}

__global__ __launch_bounds__(256) void zero_cat_state(_Float16* __restrict__ cat) {
  int i = blockIdx.x * blockDim.x + threadIdx.x;  // one half8 per thread
  int row = i >> 7;
  int c8 = (i & 127) << 3;
  half8 z = {(_Float16)0, (_Float16)0, (_Float16)0, (_Float16)0,
             (_Float16)0, (_Float16)0, (_Float16)0, (_Float16)0};
  *(half8*)(cat + (size_t)row * 1536 + c8) = z;
}

extern "C" void kernel_launch(void* const* d_in, const int* in_sizes, int n_in,
                              void* d_out, int out_size, void* d_ws,
                              size_t ws_size, hipStream_t stream) {
  const float* z  = (const float*)d_in[0];
  const float* td = (const float*)d_in[1];
  const float* Wb = (const float*)d_in[2];
  const float* bb = (const float*)d_in[3];
  const float* Wz = (const float*)d_in[4];
  const float* bz = (const float*)d_in[5];
  const float* W1 = (const float*)d_in[6];
  const float* b1 = (const float*)d_in[7];
  const float* W2 = (const float*)d_in[8];
  const float* b2 = (const float*)d_in[9];
  const float* W3 = (const float*)d_in[10];
  const float* b3 = (const float*)d_in[11];
  const float* Wo = (const float*)d_in[12];
  const float* bo = (const float*)d_in[13];
  float* out = (float*)d_out;

  char* ws = (char*)d_ws;
  size_t off = 0;
  auto alloc = [&](size_t bytes) {
    void* p = ws + off;
    off += (bytes + 255) & ~(size_t)255;
    return p;
  };
  _Float16* WzT  = (_Float16*)alloc((size_t)512 * 128 * 2);
  _Float16* WbT  = (_Float16*)alloc((size_t)1024 * 512 * 2);
  _Float16* W12T = (_Float16*)alloc((size_t)2048 * 1536 * 2);
  _Float16* W3T  = (_Float16*)alloc((size_t)1024 * 1536 * 2);
  _Float16* WoT  = (_Float16*)alloc((size_t)512 * 1024 * 2);
  _Float16* z_h  = (_Float16*)alloc((size_t)4096 * 128 * 2);
  _Float16* cat  = (_Float16*)alloc((size_t)4096 * 1536 * 2);
  _Float16* cat2 = (_Float16*)alloc((size_t)4096 * 1536 * 2);
  _Float16* u_h  = (_Float16*)alloc((size_t)4096 * 1024 * 2);
  _Float16* st_h = (_Float16*)alloc((size_t)4096 * 1024 * 2);
  if (off > ws_size) return;  // not enough scratch: fail cleanly

  dim3 blk(256);
  transpose_cvt<<<dim3(16, 4), blk, 0, stream>>>(Wz, WzT, 128, 512);
  transpose_cvt<<<dim3(32, 16), blk, 0, stream>>>(Wb, WbT, 512, 1024);
  transpose_cvt<<<dim3(32, 48), blk, 0, stream>>>(W1, W12T, 1536, 1024);
  transpose_cvt<<<dim3(32, 48), blk, 0, stream>>>(W2, W12T + (size_t)1024 * 1536,
                                                  1536, 1024);
  transpose_cvt<<<dim3(32, 48), blk, 0, stream>>>(W3, W3T, 1536, 1024);
  transpose_cvt<<<dim3(16, 32), blk, 0, stream>>>(Wo, WoT, 1024, 512);
  cvt_f16<<<256, 256, 0, stream>>>(z, z_h);            // 4096*128
  zero_cat_state<<<2048, 256, 0, stream>>>(cat);       // cat[:, :1024] = 0

  {  // x = z @ Wz + bz
    GArgs a{};
    a.A = z_h; a.BT = WzT; a.lda = 128; a.K = 128;
    a.bias = bz; a.cat = cat; a.cat2 = cat2;
    gemm_k<0, false><<<dim3(32, 4), blk, 0, stream>>>(a);
  }
  for (int t = 0; t < 12; ++t) {
    if (t > 0) {  // s' = exp(-relu(td_t @ Wb + bb)) * state  (t=0: s'=0)
      GArgs a{};
      a.Af = td + (size_t)t * 512; a.BT = WbT; a.lda = 6144; a.K = 512;
      a.bias = bb; a.state_h = st_h; a.cat = cat;
      gemm_k<1, true><<<dim3(32, 8), blk, 0, stream>>>(a);
    }
    {  // [u | r] = sigmoid(cat @ [W1|W2] + [b1|b2]); cat2 state-part = r*s'
      GArgs a{};
      a.A = cat; a.BT = W12T; a.lda = 1536; a.K = 1536;
      a.bias = b1; a.bias2 = b2; a.u_h = u_h; a.cat = cat; a.cat2 = cat2;
      gemm_k<2, false><<<dim3(32, 16), blk, 0, stream>>>(a);
    }
    {  // state = (1-u)*s' + u*tanh(cat2 @ W3 + b3)
      GArgs a{};
      a.A = cat2; a.BT = W3T; a.lda = 1536; a.K = 1536;
      a.bias = b3; a.cat = cat; a.u_h = u_h; a.state_h = st_h;
      gemm_k<3, false><<<dim3(32, 8), blk, 0, stream>>>(a);
    }
    {  // out_t = state @ Wout + bo -> d_out[:, t, :], next x
      GArgs a{};
      a.A = st_h; a.BT = WoT; a.lda = 1024; a.K = 1024;
      a.bias = bo; a.cat = cat; a.cat2 = cat2; a.out = out; a.t = t;
      gemm_k<4, false><<<dim3(32, 4), blk, 0, stream>>>(a);
    }
  }
}

// Round 2
// 1846.715 us; speedup vs baseline: 1.0790x; 1.0790x over previous
//
#include <hip/hip_runtime.h>

#define DEV __device__ __forceinline__

typedef _Float16 half8 __attribute__((ext_vector_type(8)));
typedef float f32x4 __attribute__((ext_vector_type(4)));

DEV void gload_lds16(const void* g, void* l) {
  __builtin_amdgcn_global_load_lds(
      (const __attribute__((address_space(1))) void*)g,
      (__attribute__((address_space(3))) void*)l, 16, 0, 0);
}

DEV float sigmoidf_(float x) { return 1.f / (1.f + __expf(-x)); }
DEV float tanh_fast(float x) { return 1.f - 2.f / (__expf(2.f * x) + 1.f); }

struct GArgs {
  const _Float16* A;   // f16 A operand (row-major, lda elements per row)
  const float* Af;     // f32 A operand (EPI5: time_delta base)
  const _Float16* BT;  // weights, transposed [N][K], row stride = K
  long lda;
  int K;
  int t;
  const float* bias;
  const float* bias2;
  _Float16* cat;     // [4096][1536] = [s' | x]
  _Float16* cat2;    // [4096][1536] = [r*s' | x]
  _Float16* u_h;     // [4096][1024]
  _Float16* state_h; // [4096][1024]
  _Float16* belta;   // [11][4096][1024]  (slice j <-> step t=j+1)
  float* out;        // [4096][12][512]
};

// 128xBN tile, BK=32, 4 waves. Each wave owns 64 x BN/2 (acc 4 x BN/32 frags
// of 16x16x32 f16 MFMA). LDS: tile as slots of 16B; logical (row m, k-group g)
// at slot m*4 + (g ^ ((m>>1)&3)) -- XOR spreads ds_read_b128 across bank
// groups while staging stays linear for global_load_lds (inverse permutation
// applied to the per-lane GLOBAL source address).
template <int EPI, bool AF32, int BN>
__global__ __launch_bounds__(256) void gemm_k(GArgs g) {
  constexpr int NJ = BN / 32;  // j-frags per wave
  __shared__ __align__(16) _Float16 As[4096];
  __shared__ __align__(16) _Float16 Bs[BN * 32];
  const int tid = threadIdx.x;
  const int lane = tid & 63;
  const int wave = tid >> 6;
  const int bm = blockIdx.x * 128;
  const int bn = blockIdx.y * BN;
  const int wm = (wave >> 1) * 64;
  const int wn = (wave & 1) * (BN / 2);
  const int fr = lane & 15;  // frag row (A) / col (B)
  const int fg = lane >> 4;  // k-group 0..3 (8 halves each)

  // staging: wave w covers chunk w (16 rows) [+ chunk w+4 when 128 rows];
  // lane d -> row chunk*16 + (d>>2), stored slot d&3
  const int d2 = lane >> 2, d3 = lane & 3;
  const int m0 = wave * 16 + d2;
  const int m1 = (wave + 4) * 16 + d2;
  const int g0 = d3 ^ ((m0 >> 1) & 3);  // logical k-group for this slot
  const int g1 = d3 ^ ((m1 >> 1) & 3);

  const _Float16* gB0 = g.BT + (size_t)(bn + m0) * g.K + g0 * 8;
  const _Float16* gB1 = (BN == 128) ? g.BT + (size_t)(bn + m1) * g.K + g1 * 8
                                    : nullptr;
  const _Float16* gA0 = nullptr;
  const _Float16* gA1 = nullptr;
  if constexpr (!AF32) {
    gA0 = g.A + (size_t)(bm + m0) * g.lda + g0 * 8;
    gA1 = g.A + (size_t)(bm + m1) * g.lda + g1 * 8;
  }
  // EPI5 (belta): block bx covers within-t rows (bx&31)*128.., t = (bx>>5)+1
  const size_t t_ofs = AF32 ? ((size_t)((blockIdx.x >> 5) + 1) * 512) : 0;
  const size_t rbase = AF32 ? ((size_t)(blockIdx.x & 31) * 128) : 0;

  const f32x4 zv = {0.f, 0.f, 0.f, 0.f};
  f32x4 acc[4][NJ];
#pragma unroll
  for (int i = 0; i < 4; ++i)
#pragma unroll
    for (int j = 0; j < NJ; ++j) acc[i][j] = zv;

  for (int k0 = 0; k0 < g.K; k0 += 32) {
    if (k0) __syncthreads();  // prev iter's LDS reads done before overwrite
    gload_lds16(gB0, Bs + wave * 512);
    gB0 += 32;
    if constexpr (BN == 128) {
      gload_lds16(gB1, Bs + (wave + 4) * 512);
      gB1 += 32;
    }
    if constexpr (!AF32) {
      gload_lds16(gA0, As + wave * 512);
      gload_lds16(gA1, As + (wave + 4) * 512);
      gA0 += 32;
      gA1 += 32;
    } else {
      // f32 -> f16 convert-on-stage from time_delta. 512 slots, 256 threads.
#pragma unroll
      for (int i = 0; i < 2; ++i) {
        int s = tid + i * 256;
        int m = s >> 2;
        int gg = (s & 3) ^ ((m >> 1) & 3);
        const float* p = g.Af + (rbase + m) * 6144 + t_ofs + k0 + gg * 8;
        float4 v0 = *(const float4*)p;
        float4 v1 = *(const float4*)(p + 4);
        half8 h;
        h[0] = (_Float16)v0.x; h[1] = (_Float16)v0.y;
        h[2] = (_Float16)v0.z; h[3] = (_Float16)v0.w;
        h[4] = (_Float16)v1.x; h[5] = (_Float16)v1.y;
        h[6] = (_Float16)v1.z; h[7] = (_Float16)v1.w;
        *(half8*)(As + s * 8) = h;
      }
    }
    __syncthreads();

    half8 af[4], bf[NJ];
#pragma unroll
    for (int i = 0; i < 4; ++i) {
      int am = wm + i * 16 + fr;
      af[i] = *(const half8*)(As + (size_t)(am * 4 + (fg ^ ((am >> 1) & 3))) * 8);
    }
#pragma unroll
    for (int j = 0; j < NJ; ++j) {
      int bb = wn + j * 16 + fr;
      bf[j] = *(const half8*)(Bs + (size_t)(bb * 4 + (fg ^ ((bb >> 1) & 3))) * 8);
    }
#pragma unroll
    for (int i = 0; i < 4; ++i)
#pragma unroll
      for (int j = 0; j < NJ; ++j)
        acc[i][j] =
            __builtin_amdgcn_mfma_f32_16x16x32_f16(af[i], bf[j], acc[i][j], 0, 0, 0);
  }

  // C/D layout (gfx950): col = lane&15, row = (lane>>4)*4 + reg
  const int row0 = bm + wm + fg * 4;
  const int col0 = bn + wn + fr;
#pragma unroll
  for (int i = 0; i < 4; ++i) {
#pragma unroll
    for (int j = 0; j < NJ; ++j) {
      const int col = col0 + j * 16;
#pragma unroll
      for (int r = 0; r < 4; ++r) {
        const int row = row0 + i * 16 + r;
        float v = acc[i][j][r];
        if constexpr (EPI == 0) {  // x = z@Wz + bz -> x-part of cat, cat2
          _Float16 h = (_Float16)(v + g.bias[col]);
          g.cat[(size_t)row * 1536 + 1024 + col] = h;
          g.cat2[(size_t)row * 1536 + 1024 + col] = h;
        } else if constexpr (EPI == 2) {  // u (cols<1024) | r*s' (cols>=1024)
          if (col < 1024) {
            g.u_h[(size_t)row * 1024 + col] =
                (_Float16)sigmoidf_(v + g.bias[col]);
          } else {
            int c = col - 1024;
            float rr = sigmoidf_(v + g.bias2[c]);
            float sp = (float)g.cat[(size_t)row * 1536 + c];
            g.cat2[(size_t)row * 1536 + c] = (_Float16)(rr * sp);
          }
        } else if constexpr (EPI == 3) {
          // state = (1-u)s' + u*tanh(v+b3); also s'_{t+1} = belta_{t+1}*state
          float ns = tanh_fast(v + g.bias[col]);
          size_t rc = (size_t)row * 1536 + col;
          float sp = (float)g.cat[rc];
          float u = (float)g.u_h[(size_t)row * 1024 + col];
          float st = (1.f - u) * sp + u * ns;
          g.state_h[(size_t)row * 1024 + col] = (_Float16)st;
          if (g.t < 11) {
            float bl = (float)g.belta[(size_t)g.t * 4194304 +
                                      (size_t)row * 1024 + col];
            g.cat[rc] = (_Float16)(bl * st);
          }
        } else if constexpr (EPI == 4) {  // out = state@Wout + bo
          float o = v + g.bias[col];
          g.out[((size_t)row * 12 + g.t) * 512 + col] = o;
          _Float16 h = (_Float16)o;
          g.cat[(size_t)row * 1536 + 1024 + col] = h;
          g.cat2[(size_t)row * 1536 + 1024 + col] = h;
        } else {  // EPI 5: belta_all = exp(-relu(td@Wb + bb)), rows 0..45055
          g.belta[(size_t)row * 1024 + col] =
              (_Float16)__expf(-fmaxf(0.f, v + g.bias[col]));
        }
      }
    }
  }
}

// f32 [K][N] row-major -> f16 [N][K] (transposed) via 32x32 LDS tile
__global__ __launch_bounds__(256) void transpose_cvt(const float* __restrict__ src,
                                                     _Float16* __restrict__ dst,
                                                     int K, int N) {
  __shared__ float tile[32][33];
  const int nb = blockIdx.x * 32;
  const int kb = blockIdx.y * 32;
  const int tx = threadIdx.x & 31;
  const int ty = threadIdx.x >> 5;
#pragma unroll
  for (int i = ty; i < 32; i += 8)
    tile[i][tx] = src[(size_t)(kb + i) * N + nb + tx];
  __syncthreads();
#pragma unroll
  for (int i = ty; i < 32; i += 8)
    dst[(size_t)(nb + i) * K + kb + tx] = (_Float16)tile[tx][i];
}

__global__ __launch_bounds__(256) void cvt_f16(const float* __restrict__ src,
                                               _Float16* __restrict__ dst) {
  int i = blockIdx.x * blockDim.x + threadIdx.x;
  const float4* p = (const float4*)(src + (size_t)i * 8);
  float4 a = p[0], b = p[1];
  half8 h;
  h[0] = (_Float16)a.x; h[1] = (_Float16)a.y;
  h[2] = (_Float16)a.z; h[3] = (_Float16)a.w;
  h[4] = (_Float16)b.x; h[5] = (_Float16)b.y;
  h[6] = (_Float16)b.z; h[7] = (_Float16)b.w;
  *(half8*)(dst + (size_t)i * 8) = h;
}

__global__ __launch_bounds__(256) void zero_cat_state(_Float16* __restrict__ cat) {
  int i = blockIdx.x * blockDim.x + threadIdx.x;  // one half8 per thread
  int row = i >> 7;
  int c8 = (i & 127) << 3;
  half8 z = {(_Float16)0, (_Float16)0, (_Float16)0, (_Float16)0,
             (_Float16)0, (_Float16)0, (_Float16)0, (_Float16)0};
  *(half8*)(cat + (size_t)row * 1536 + c8) = z;
}

extern "C" void kernel_launch(void* const* d_in, const int* in_sizes, int n_in,
                              void* d_out, int out_size, void* d_ws,
                              size_t ws_size, hipStream_t stream) {
  const float* z  = (const float*)d_in[0];
  const float* td = (const float*)d_in[1];
  const float* Wb = (const float*)d_in[2];
  const float* bb = (const float*)d_in[3];
  const float* Wz = (const float*)d_in[4];
  const float* bz = (const float*)d_in[5];
  const float* W1 = (const float*)d_in[6];
  const float* b1 = (const float*)d_in[7];
  const float* W2 = (const float*)d_in[8];
  const float* b2 = (const float*)d_in[9];
  const float* W3 = (const float*)d_in[10];
  const float* b3 = (const float*)d_in[11];
  const float* Wo = (const float*)d_in[12];
  const float* bo = (const float*)d_in[13];
  float* out = (float*)d_out;

  char* ws = (char*)d_ws;
  size_t off = 0;
  auto alloc = [&](size_t bytes) {
    void* p = ws + off;
    off += (bytes + 255) & ~(size_t)255;
    return p;
  };
  _Float16* WzT  = (_Float16*)alloc((size_t)512 * 128 * 2);
  _Float16* WbT  = (_Float16*)alloc((size_t)1024 * 512 * 2);
  _Float16* W12T = (_Float16*)alloc((size_t)2048 * 1536 * 2);
  _Float16* W3T  = (_Float16*)alloc((size_t)1024 * 1536 * 2);
  _Float16* WoT  = (_Float16*)alloc((size_t)512 * 1024 * 2);
  _Float16* z_h  = (_Float16*)alloc((size_t)4096 * 128 * 2);
  _Float16* cat  = (_Float16*)alloc((size_t)4096 * 1536 * 2);
  _Float16* cat2 = (_Float16*)alloc((size_t)4096 * 1536 * 2);
  _Float16* u_h  = (_Float16*)alloc((size_t)4096 * 1024 * 2);
  _Float16* st_h = (_Float16*)alloc((size_t)4096 * 1024 * 2);
  _Float16* beltaA = (_Float16*)alloc((size_t)11 * 4096 * 1024 * 2);
  if (off > ws_size) return;  // not enough scratch: fail cleanly

  dim3 blk(256);
  transpose_cvt<<<dim3(16, 4), blk, 0, stream>>>(Wz, WzT, 128, 512);
  transpose_cvt<<<dim3(32, 16), blk, 0, stream>>>(Wb, WbT, 512, 1024);
  transpose_cvt<<<dim3(32, 48), blk, 0, stream>>>(W1, W12T, 1536, 1024);
  transpose_cvt<<<dim3(32, 48), blk, 0, stream>>>(W2, W12T + (size_t)1024 * 1536,
                                                  1536, 1024);
  transpose_cvt<<<dim3(32, 48), blk, 0, stream>>>(W3, W3T, 1536, 1024);
  transpose_cvt<<<dim3(16, 32), blk, 0, stream>>>(Wo, WoT, 1024, 512);
  cvt_f16<<<256, 256, 0, stream>>>(z, z_h);            // 4096*128
  zero_cat_state<<<2048, 256, 0, stream>>>(cat);       // cat[:, :1024] = 0

  {  // belta (t=1..11) in one parallel GEMM: M=45056, N=1024, K=512
    GArgs a{};
    a.Af = td; a.BT = WbT; a.K = 512; a.bias = bb; a.belta = beltaA;
    gemm_k<5, true, 128><<<dim3(352, 8), blk, 0, stream>>>(a);
  }
  {  // x = z @ Wz + bz
    GArgs a{};
    a.A = z_h; a.BT = WzT; a.lda = 128; a.K = 128;
    a.bias = bz; a.cat = cat; a.cat2 = cat2;
    gemm_k<0, false, 64><<<dim3(32, 8), blk, 0, stream>>>(a);
  }
  for (int t = 0; t < 12; ++t) {
    {  // [u | r] = sigmoid(cat @ [W1|W2] + [b1|b2]); cat2 state-part = r*s'
      GArgs a{};
      a.A = cat; a.BT = W12T; a.lda = 1536; a.K = 1536;
      a.bias = b1; a.bias2 = b2; a.u_h = u_h; a.cat = cat; a.cat2 = cat2;
      gemm_k<2, false, 128><<<dim3(32, 16), blk, 0, stream>>>(a);
    }
    {  // state = (1-u)*s' + u*tanh(cat2 @ W3 + b3); s'_{t+1} = belta*state
      GArgs a{};
      a.A = cat2; a.BT = W3T; a.lda = 1536; a.K = 1536;
      a.bias = b3; a.cat = cat; a.u_h = u_h; a.state_h = st_h;
      a.belta = beltaA; a.t = t;
      gemm_k<3, false, 128><<<dim3(32, 8), blk, 0, stream>>>(a);
    }
    {  // out_t = state @ Wout + bo -> d_out[:, t, :], next x
      GArgs a{};
      a.A = st_h; a.BT = WoT; a.lda = 1024; a.K = 1024;
      a.bias = bo; a.cat = cat; a.cat2 = cat2; a.out = out; a.t = t;
      gemm_k<4, false, 64><<<dim3(32, 8), blk, 0, stream>>>(a);
    }
  }
}

// Round 3
// 1541.528 us; speedup vs baseline: 1.2926x; 1.1980x over previous
//
#include <hip/hip_runtime.h>

#define DEV __device__ __forceinline__

typedef _Float16 half8 __attribute__((ext_vector_type(8)));
typedef float f32x4 __attribute__((ext_vector_type(4)));

DEV void gload_lds16(const void* g, void* l) {
  __builtin_amdgcn_global_load_lds(
      (const __attribute__((address_space(1))) void*)g,
      (__attribute__((address_space(3))) void*)l, 16, 0, 0);
}

DEV float sigmoidf_(float x) { return 1.f / (1.f + __expf(-x)); }
DEV float tanh_fast(float x) { return 1.f - 2.f / (__expf(2.f * x) + 1.f); }

struct GArgs {
  const _Float16* A;   // f16 A operand (row-major, lda elements per row)
  const float* Af;     // f32 A operand (EPI5: time_delta base)
  const _Float16* BT;  // weights, transposed [N][K], row stride = K
  long lda;
  int K;
  int t;
  // XCD swizzle: tile grid is (8/XC * RM) x (XC * RN); xcd gets an RMxRN region
  int XC, RM, RN;
  const float* bias;
  const float* bias2;
  _Float16* cat;     // [4096][1536] = [s' | x]
  _Float16* cat2;    // [4096][1536] = [r*s' | x]
  _Float16* u_h;     // [4096][1024]
  _Float16* state_h; // [4096][1024]
  _Float16* belta;   // [11][4096][1024]  (slice j <-> step t=j+1)
  float* out;        // [4096][12][512]
};

// 128xBN tile, BK=32, 4 waves. Each wave owns 64 x BN/2 (acc 4 x BN/32 frags
// of 16x16x32 f16 MFMA). Staging LDS: 16B slots, logical (row m, k-group g) at
// slot m*4 + (g ^ ((m>>1)&3)); inverse permutation applied on the GLOBAL src
// address so global_load_lds dest stays linear. Epilogue: acc -> LDS (f16,
// aliased over staging buffers) -> vectorized half8 global stores.
template <int EPI, bool AF32, int BN>
__global__ __launch_bounds__(256) void gemm_k(GArgs g) {
  constexpr int NJ = BN / 32;  // j-frags per wave
  constexpr int STAGE_B = (4096 + BN * 32) * 2;
  constexpr int C_B = 128 * BN * 2;
  constexpr int SMEM_B = STAGE_B > C_B ? STAGE_B : C_B;
  __shared__ __align__(16) char smem[SMEM_B];
  _Float16* As = (_Float16*)smem;
  _Float16* Bs = As + 4096;
  _Float16* Cs = (_Float16*)smem;  // aliased; barrier-separated

  const int tid = threadIdx.x;
  const int lane = tid & 63;
  const int wave = tid >> 6;

  // XCD-aware bijective swizzle: consecutive work within one XCD's L2
  const int bid = blockIdx.x;
  const int xcd = bid & 7;
  const int k = bid >> 3;
  const int tm = (xcd / g.XC) * g.RM + k / g.RN;
  const int tn = (xcd % g.XC) * g.RN + k % g.RN;
  const int bm = tm * 128;
  const int bn = tn * BN;

  const int wm = (wave >> 1) * 64;
  const int wn = (wave & 1) * (BN / 2);
  const int fr = lane & 15;  // frag row (A) / col (B)
  const int fg = lane >> 4;  // k-group 0..3 (8 halves each)

  // staging: wave w covers chunk w (16 rows) [+ chunk w+4 when BN==128 for B];
  // lane d -> row chunk*16 + (d>>2), stored slot d&3
  const int d2 = lane >> 2, d3 = lane & 3;
  const int m0 = wave * 16 + d2;
  const int m1 = (wave + 4) * 16 + d2;
  const int g0 = d3 ^ ((m0 >> 1) & 3);  // logical k-group for this slot
  const int g1 = d3 ^ ((m1 >> 1) & 3);

  const _Float16* gB0 = g.BT + (size_t)(bn + m0) * g.K + g0 * 8;
  const _Float16* gB1 = (BN == 128) ? g.BT + (size_t)(bn + m1) * g.K + g1 * 8
                                    : nullptr;
  const _Float16* gA0 = nullptr;
  const _Float16* gA1 = nullptr;
  if constexpr (!AF32) {
    gA0 = g.A + (size_t)(bm + m0) * g.lda + g0 * 8;
    gA1 = g.A + (size_t)(bm + m1) * g.lda + g1 * 8;
  }
  // EPI5 (belta): tile-row tm encodes (t-1)*32 + within-t row-block
  const size_t t_ofs = AF32 ? (size_t)((tm >> 5) + 1) * 512 : 0;
  const size_t rbase = AF32 ? (size_t)(tm & 31) * 128 : 0;

  const f32x4 zv = {0.f, 0.f, 0.f, 0.f};
  f32x4 acc[4][NJ];
#pragma unroll
  for (int i = 0; i < 4; ++i)
#pragma unroll
    for (int j = 0; j < NJ; ++j) acc[i][j] = zv;

  for (int k0 = 0; k0 < g.K; k0 += 32) {
    if (k0) __syncthreads();  // prev iter's LDS reads done before overwrite
    gload_lds16(gB0, Bs + wave * 512);
    gB0 += 32;
    if constexpr (BN == 128) {
      gload_lds16(gB1, Bs + (wave + 4) * 512);
      gB1 += 32;
    }
    if constexpr (!AF32) {
      gload_lds16(gA0, As + wave * 512);
      gload_lds16(gA1, As + (wave + 4) * 512);
      gA0 += 32;
      gA1 += 32;
    } else {
      // f32 -> f16 convert-on-stage from time_delta. 512 slots, 256 threads.
#pragma unroll
      for (int i = 0; i < 2; ++i) {
        int s = tid + i * 256;
        int m = s >> 2;
        int gg = (s & 3) ^ ((m >> 1) & 3);
        const float* p = g.Af + (rbase + m) * 6144 + t_ofs + k0 + gg * 8;
        float4 v0 = *(const float4*)p;
        float4 v1 = *(const float4*)(p + 4);
        half8 h;
        h[0] = (_Float16)v0.x; h[1] = (_Float16)v0.y;
        h[2] = (_Float16)v0.z; h[3] = (_Float16)v0.w;
        h[4] = (_Float16)v1.x; h[5] = (_Float16)v1.y;
        h[6] = (_Float16)v1.z; h[7] = (_Float16)v1.w;
        *(half8*)(As + s * 8) = h;
      }
    }
    __syncthreads();

    half8 af[4], bf[NJ];
#pragma unroll
    for (int i = 0; i < 4; ++i) {
      int am = wm + i * 16 + fr;
      af[i] = *(const half8*)(As + (size_t)(am * 4 + (fg ^ ((am >> 1) & 3))) * 8);
    }
#pragma unroll
    for (int j = 0; j < NJ; ++j) {
      int bb = wn + j * 16 + fr;
      bf[j] = *(const half8*)(Bs + (size_t)(bb * 4 + (fg ^ ((bb >> 1) & 3))) * 8);
    }
#pragma unroll
    for (int i = 0; i < 4; ++i)
#pragma unroll
      for (int j = 0; j < NJ; ++j)
        acc[i][j] =
            __builtin_amdgcn_mfma_f32_16x16x32_f16(af[i], bf[j], acc[i][j], 0, 0, 0);
  }

  // ---- epilogue phase 1: activation math on f32 acc, stage f16 tile to LDS
  // C/D layout (gfx950): col = lane&15, row = (lane>>4)*4 + reg
  __syncthreads();  // all frag reads done; Cs aliases As/Bs
  const int row0l = wm + fg * 4;
  const int col0l = wn + fr;
#pragma unroll
  for (int i = 0; i < 4; ++i) {
#pragma unroll
    for (int j = 0; j < NJ; ++j) {
      const int cl = col0l + j * 16;
      const int col = bn + cl;
#pragma unroll
      for (int r = 0; r < 4; ++r) {
        const int rl = row0l + i * 16 + r;
        float v = acc[i][j][r];
        float val;
        if constexpr (EPI == 0) {
          val = v + g.bias[col];
        } else if constexpr (EPI == 2) {
          float b = (bn < 1024) ? g.bias[col] : g.bias2[col - 1024];
          val = sigmoidf_(v + b);
        } else if constexpr (EPI == 3) {
          val = tanh_fast(v + g.bias[col]);
        } else if constexpr (EPI == 4) {
          val = v + g.bias[col];
        } else {  // EPI 5
          val = __expf(-fmaxf(0.f, v + g.bias[col]));
        }
        Cs[rl * BN + cl] = (_Float16)val;
      }
    }
  }
  __syncthreads();

  // ---- epilogue phase 2: vectorized half8 global traffic
  constexpr int CPR = BN / 8;  // 16B chunks per row
#pragma unroll
  for (int c = tid; c < 128 * CPR; c += 256) {
    const int row = c / CPR;
    const int off8 = (c % CPR) * 8;
    const int row_g = bm + row;
    half8 hv = *(const half8*)(Cs + row * BN + off8);
    if constexpr (EPI == 0) {  // x-part of cat, cat2
      *(half8*)(g.cat + (size_t)row_g * 1536 + 1024 + bn + off8) = hv;
      *(half8*)(g.cat2 + (size_t)row_g * 1536 + 1024 + bn + off8) = hv;
    } else if constexpr (EPI == 2) {
      if (bn < 1024) {  // u
        *(half8*)(g.u_h + (size_t)row_g * 1024 + bn + off8) = hv;
      } else {  // cat2 state-part = r * s'
        const int cc = bn - 1024 + off8;
        half8 sp = *(const half8*)(g.cat + (size_t)row_g * 1536 + cc);
        half8 o;
#pragma unroll
        for (int e = 0; e < 8; ++e) o[e] = (_Float16)((float)hv[e] * (float)sp[e]);
        *(half8*)(g.cat2 + (size_t)row_g * 1536 + cc) = o;
      }
    } else if constexpr (EPI == 3) {
      // hv = tanh(...); state = (1-u)s' + u*hv; s'_{t+1} = belta_{t+1}*state
      half8 sp = *(const half8*)(g.cat + (size_t)row_g * 1536 + bn + off8);
      half8 uu = *(const half8*)(g.u_h + (size_t)row_g * 1024 + bn + off8);
      half8 st;
#pragma unroll
      for (int e = 0; e < 8; ++e) {
        float u = (float)uu[e];
        st[e] = (_Float16)((1.f - u) * (float)sp[e] + u * (float)hv[e]);
      }
      *(half8*)(g.state_h + (size_t)row_g * 1024 + bn + off8) = st;
      if (g.t < 11) {
        half8 bl = *(const half8*)(g.belta + (size_t)g.t * 4194304 +
                                   (size_t)row_g * 1024 + bn + off8);
        half8 ns;
#pragma unroll
        for (int e = 0; e < 8; ++e)
          ns[e] = (_Float16)((float)bl[e] * (float)st[e]);
        *(half8*)(g.cat + (size_t)row_g * 1536 + bn + off8) = ns;
      }
    } else if constexpr (EPI == 4) {  // out (f32) + next x (f16)
      *(half8*)(g.cat + (size_t)row_g * 1536 + 1024 + bn + off8) = hv;
      *(half8*)(g.cat2 + (size_t)row_g * 1536 + 1024 + bn + off8) = hv;
      float* op = g.out + ((size_t)row_g * 12 + g.t) * 512 + bn + off8;
      float4 f0, f1;
      f0.x = (float)hv[0]; f0.y = (float)hv[1];
      f0.z = (float)hv[2]; f0.w = (float)hv[3];
      f1.x = (float)hv[4]; f1.y = (float)hv[5];
      f1.z = (float)hv[6]; f1.w = (float)hv[7];
      *(float4*)op = f0;
      *(float4*)(op + 4) = f1;
    } else {  // EPI 5: belta rows are tm*128 + row
      *(half8*)(g.belta + (size_t)row_g * 1024 + bn + off8) = hv;
    }
  }
}

// f32 [K][N] row-major -> f16 [N][K] (transposed) via 32x32 LDS tile
__global__ __launch_bounds__(256) void transpose_cvt(const float* __restrict__ src,
                                                     _Float16* __restrict__ dst,
                                                     int K, int N) {
  __shared__ float tile[32][33];
  const int nb = blockIdx.x * 32;
  const int kb = blockIdx.y * 32;
  const int tx = threadIdx.x & 31;
  const int ty = threadIdx.x >> 5;
#pragma unroll
  for (int i = ty; i < 32; i += 8)
    tile[i][tx] = src[(size_t)(kb + i) * N + nb + tx];
  __syncthreads();
#pragma unroll
  for (int i = ty; i < 32; i += 8)
    dst[(size_t)(nb + i) * K + kb + tx] = (_Float16)tile[tx][i];
}

__global__ __launch_bounds__(256) void cvt_f16(const float* __restrict__ src,
                                               _Float16* __restrict__ dst) {
  int i = blockIdx.x * blockDim.x + threadIdx.x;
  const float4* p = (const float4*)(src + (size_t)i * 8);
  float4 a = p[0], b = p[1];
  half8 h;
  h[0] = (_Float16)a.x; h[1] = (_Float16)a.y;
  h[2] = (_Float16)a.z; h[3] = (_Float16)a.w;
  h[4] = (_Float16)b.x; h[5] = (_Float16)b.y;
  h[6] = (_Float16)b.z; h[7] = (_Float16)b.w;
  *(half8*)(dst + (size_t)i * 8) = h;
}

__global__ __launch_bounds__(256) void zero_cat_state(_Float16* __restrict__ cat) {
  int i = blockIdx.x * blockDim.x + threadIdx.x;  // one half8 per thread
  int row = i >> 7;
  int c8 = (i & 127) << 3;
  half8 z = {(_Float16)0, (_Float16)0, (_Float16)0, (_Float16)0,
             (_Float16)0, (_Float16)0, (_Float16)0, (_Float16)0};
  *(half8*)(cat + (size_t)row * 1536 + c8) = z;
}

extern "C" void kernel_launch(void* const* d_in, const int* in_sizes, int n_in,
                              void* d_out, int out_size, void* d_ws,
                              size_t ws_size, hipStream_t stream) {
  const float* z  = (const float*)d_in[0];
  const float* td = (const float*)d_in[1];
  const float* Wb = (const float*)d_in[2];
  const float* bb = (const float*)d_in[3];
  const float* Wz = (const float*)d_in[4];
  const float* bz = (const float*)d_in[5];
  const float* W1 = (const float*)d_in[6];
  const float* b1 = (const float*)d_in[7];
  const float* W2 = (const float*)d_in[8];
  const float* b2 = (const float*)d_in[9];
  const float* W3 = (const float*)d_in[10];
  const float* b3 = (const float*)d_in[11];
  const float* Wo = (const float*)d_in[12];
  const float* bo = (const float*)d_in[13];
  float* out = (float*)d_out;

  char* ws = (char*)d_ws;
  size_t off = 0;
  auto alloc = [&](size_t bytes) {
    void* p = ws + off;
    off += (bytes + 255) & ~(size_t)255;
    return p;
  };
  _Float16* WzT  = (_Float16*)alloc((size_t)512 * 128 * 2);
  _Float16* WbT  = (_Float16*)alloc((size_t)1024 * 512 * 2);
  _Float16* W12T = (_Float16*)alloc((size_t)2048 * 1536 * 2);
  _Float16* W3T  = (_Float16*)alloc((size_t)1024 * 1536 * 2);
  _Float16* WoT  = (_Float16*)alloc((size_t)512 * 1024 * 2);
  _Float16* z_h  = (_Float16*)alloc((size_t)4096 * 128 * 2);
  _Float16* cat  = (_Float16*)alloc((size_t)4096 * 1536 * 2);
  _Float16* cat2 = (_Float16*)alloc((size_t)4096 * 1536 * 2);
  _Float16* u_h  = (_Float16*)alloc((size_t)4096 * 1024 * 2);
  _Float16* st_h = (_Float16*)alloc((size_t)4096 * 1024 * 2);
  _Float16* beltaA = (_Float16*)alloc((size_t)11 * 4096 * 1024 * 2);
  if (off > ws_size) return;  // not enough scratch: fail cleanly

  dim3 blk(256);
  transpose_cvt<<<dim3(16, 4), blk, 0, stream>>>(Wz, WzT, 128, 512);
  transpose_cvt<<<dim3(32, 16), blk, 0, stream>>>(Wb, WbT, 512, 1024);
  transpose_cvt<<<dim3(32, 48), blk, 0, stream>>>(W1, W12T, 1536, 1024);
  transpose_cvt<<<dim3(32, 48), blk, 0, stream>>>(W2, W12T + (size_t)1024 * 1536,
                                                  1536, 1024);
  transpose_cvt<<<dim3(32, 48), blk, 0, stream>>>(W3, W3T, 1536, 1024);
  transpose_cvt<<<dim3(16, 32), blk, 0, stream>>>(Wo, WoT, 1024, 512);
  cvt_f16<<<256, 256, 0, stream>>>(z, z_h);            // 4096*128
  zero_cat_state<<<2048, 256, 0, stream>>>(cat);       // cat[:, :1024] = 0

  {  // belta (t=1..11) in one parallel GEMM: M=45056, N=1024, K=512
    GArgs a{};
    a.Af = td; a.BT = WbT; a.K = 512; a.bias = bb; a.belta = beltaA;
    a.XC = 1; a.RM = 44; a.RN = 8;   // tile grid 352 x 8
    gemm_k<5, true, 128><<<2816, blk, 0, stream>>>(a);
  }
  {  // x = z @ Wz + bz
    GArgs a{};
    a.A = z_h; a.BT = WzT; a.lda = 128; a.K = 128;
    a.bias = bz; a.cat = cat; a.cat2 = cat2;
    a.XC = 1; a.RM = 4; a.RN = 8;    // tile grid 32 x 8 (BN=64)
    gemm_k<0, false, 64><<<256, blk, 0, stream>>>(a);
  }
  for (int t = 0; t < 12; ++t) {
    {  // [u | r] = sigmoid(cat @ [W1|W2] + [b1|b2]); cat2 state-part = r*s'
      GArgs a{};
      a.A = cat; a.BT = W12T; a.lda = 1536; a.K = 1536;
      a.bias = b1; a.bias2 = b2; a.u_h = u_h; a.cat = cat; a.cat2 = cat2;
      a.XC = 2; a.RM = 8; a.RN = 8;  // tile grid 32 x 16
      gemm_k<2, false, 128><<<512, blk, 0, stream>>>(a);
    }
    {  // state = (1-u)*s' + u*tanh(cat2 @ W3 + b3); s'_{t+1} = belta*state
      GArgs a{};
      a.A = cat2; a.BT = W3T; a.lda = 1536; a.K = 1536;
      a.bias = b3; a.cat = cat; a.u_h = u_h; a.state_h = st_h;
      a.belta = beltaA; a.t = t;
      a.XC = 2; a.RM = 8; a.RN = 4;  // tile grid 32 x 8
      gemm_k<3, false, 128><<<256, blk, 0, stream>>>(a);
    }
    {  // out_t = state @ Wout + bo -> d_out[:, t, :], next x
      GArgs a{};
      a.A = st_h; a.BT = WoT; a.lda = 1024; a.K = 1024;
      a.bias = bo; a.cat = cat; a.cat2 = cat2; a.out = out; a.t = t;
      a.XC = 2; a.RM = 8; a.RN = 4;  // tile grid 32 x 8 (BN=64)
      gemm_k<4, false, 64><<<256, blk, 0, stream>>>(a);
    }
  }
}

// Round 5
// 1450.196 us; speedup vs baseline: 1.3740x; 1.0630x over previous
//
#include <hip/hip_runtime.h>

#define DEV __device__ __forceinline__

typedef _Float16 half8 __attribute__((ext_vector_type(8)));
typedef float f32x4 __attribute__((ext_vector_type(4)));

DEV void gload_lds16(const void* g, void* l) {
  __builtin_amdgcn_global_load_lds(
      (const __attribute__((address_space(1))) void*)g,
      (__attribute__((address_space(3))) void*)l, 16, 0, 0);
}

DEV float sigmoidf_(float x) { return 1.f / (1.f + __expf(-x)); }
DEV float tanh_fast(float x) { return 1.f - 2.f / (__expf(2.f * x) + 1.f); }

struct GArgs {
  const _Float16* A;   // f16 A operand (row-major, lda elems/row; EPI5: td_h)
  const _Float16* BT;  // weights, transposed [N][K], row stride = K
  long lda;
  int K;
  int t;
  // XCD swizzle: tile grid is (8/XC * RM) x (XC * RN); xcd owns an RMxRN region
  int XC, RM, RN;
  const float* bias;
  const float* bias2;
  _Float16* cat;     // [4096][1536] = [s' | x]
  _Float16* cat2;    // [4096][1536] = [r*s' | x]
  _Float16* u_h;     // [4096][1024]
  _Float16* state_h; // [4096][1024]
  _Float16* belta;   // [11][4096][1024]  (slice j <-> step t=j+1)
  float* out;        // [4096][12][512]
};

// BMxBN tile, BK=32, 4 waves (2x2), wave = (BM/2)x(BN/2) via MIxNJ frags of
// 16x16x32 f16 MFMA. Staging LDS: 16B slots; logical (row m, k-group g) at
// slot m*4 + (g ^ ((m>>1)&3)); inverse permutation applied on the GLOBAL src
// address so global_load_lds dest stays linear. Epilogue: acc -> LDS f16 tile
// (aliased over staging, barrier-separated) -> vectorized half8 global I/O.
template <int EPI, int BM, int BN>
__global__ __launch_bounds__(256) void gemm_k(GArgs g) {
  constexpr int MI = BM / 32;  // i-frags per wave
  constexpr int NJ = BN / 32;  // j-frags per wave
  constexpr int STAGE_B = (BM * 32 + BN * 32) * 2;
  constexpr int C_B = BM * BN * 2;
  constexpr int SMEM_B = STAGE_B > C_B ? STAGE_B : C_B;
  __shared__ __align__(16) char smem[SMEM_B];
  _Float16* As = (_Float16*)smem;
  _Float16* Bs = As + BM * 32;
  _Float16* Cs = (_Float16*)smem;  // aliased; barrier-separated

  const int tid = threadIdx.x;
  const int lane = tid & 63;
  const int wave = tid >> 6;

  // XCD-aware bijective swizzle: consecutive work within one XCD's L2;
  // k/RN ordering keeps one A-panel + the region's B-panels L2-resident.
  const int bid = blockIdx.x;
  const int xcd = bid & 7;
  const int k = bid >> 3;
  const int tm = (xcd / g.XC) * g.RM + k / g.RN;
  const int tn = (xcd % g.XC) * g.RN + k % g.RN;
  const int bm = tm * BM;
  const int bn = tn * BN;

  const int wm = (wave >> 1) * (BM / 2);
  const int wn = (wave & 1) * (BN / 2);
  const int fr = lane & 15;  // frag row (A) / col (B)
  const int fg = lane >> 4;  // k-group 0..3 (8 halves each)

  // staging: chunk w = 16 rows; lane d -> row chunk*16 + (d>>2), slot d&3
  const int d2 = lane >> 2, d3 = lane & 3;
  const int m0 = wave * 16 + d2;
  const int m1 = (wave + 4) * 16 + d2;
  const int g0 = d3 ^ ((m0 >> 1) & 3);  // logical k-group for this slot
  const int g1 = d3 ^ ((m1 >> 1) & 3);

  const _Float16* gB0 = g.BT + (size_t)(bn + m0) * g.K + g0 * 8;
  const _Float16* gB1 = (BN == 128) ? g.BT + (size_t)(bn + m1) * g.K + g1 * 8
                                    : nullptr;
  const _Float16* gA0;
  const _Float16* gA1 = nullptr;
  if constexpr (EPI == 5) {
    // A = td_h[b][t][512]: tile-row tm = (t-1)*32 + within-t row-block
    const int t = (tm >> 5) + 1;
    const size_t rb = (size_t)(tm & 31) * 128;
    gA0 = g.A + (rb + m0) * 6144 + t * 512 + g0 * 8;
    gA1 = g.A + (rb + m1) * 6144 + t * 512 + g1 * 8;
  } else {
    gA0 = g.A + (size_t)(bm + m0) * g.lda + g0 * 8;
    if constexpr (BM == 128)
      gA1 = g.A + (size_t)(bm + m1) * g.lda + g1 * 8;
  }

  const f32x4 zv = {0.f, 0.f, 0.f, 0.f};
  f32x4 acc[MI][NJ];
#pragma unroll
  for (int i = 0; i < MI; ++i)
#pragma unroll
    for (int j = 0; j < NJ; ++j) acc[i][j] = zv;

  for (int k0 = 0; k0 < g.K; k0 += 32) {
    if (k0) __syncthreads();  // prev iter's LDS reads done before overwrite
    gload_lds16(gB0, Bs + wave * 512);
    gB0 += 32;
    if constexpr (BN == 128) {
      gload_lds16(gB1, Bs + (wave + 4) * 512);
      gB1 += 32;
    }
    gload_lds16(gA0, As + wave * 512);
    gA0 += 32;
    if constexpr (BM == 128) {
      gload_lds16(gA1, As + (wave + 4) * 512);
      gA1 += 32;
    }
    __syncthreads();

    half8 af[MI], bf[NJ];
#pragma unroll
    for (int i = 0; i < MI; ++i) {
      int am = wm + i * 16 + fr;
      af[i] = *(const half8*)(As + (size_t)(am * 4 + (fg ^ ((am >> 1) & 3))) * 8);
    }
#pragma unroll
    for (int j = 0; j < NJ; ++j) {
      int bb = wn + j * 16 + fr;
      bf[j] = *(const half8*)(Bs + (size_t)(bb * 4 + (fg ^ ((bb >> 1) & 3))) * 8);
    }
#pragma unroll
    for (int i = 0; i < MI; ++i)
#pragma unroll
      for (int j = 0; j < NJ; ++j)
        acc[i][j] =
            __builtin_amdgcn_mfma_f32_16x16x32_f16(af[i], bf[j], acc[i][j], 0, 0, 0);
  }

  // ---- epilogue phase 1: activation math on f32 acc, stage f16 tile to LDS
  // C/D layout (gfx950): col = lane&15, row = (lane>>4)*4 + reg
  __syncthreads();  // all frag reads done; Cs aliases As/Bs
  const int row0l = wm + fg * 4;
  const int col0l = wn + fr;
#pragma unroll
  for (int i = 0; i < MI; ++i) {
#pragma unroll
    for (int j = 0; j < NJ; ++j) {
      const int cl = col0l + j * 16;
      const int col = bn + cl;
#pragma unroll
      for (int r = 0; r < 4; ++r) {
        const int rl = row0l + i * 16 + r;
        float v = acc[i][j][r];
        float val;
        if constexpr (EPI == 0) {
          val = v + g.bias[col];
        } else if constexpr (EPI == 2) {
          float b = (col < 1024) ? g.bias[col] : g.bias2[col - 1024];
          val = sigmoidf_(v + b);
        } else if constexpr (EPI == 3) {
          val = tanh_fast(v + g.bias[col]);
        } else if constexpr (EPI == 4) {
          val = v + g.bias[col];
        } else {  // EPI 5
          val = __expf(-fmaxf(0.f, v + g.bias[col]));
        }
        Cs[rl * BN + cl] = (_Float16)val;
      }
    }
  }
  __syncthreads();

  // ---- epilogue phase 2: vectorized half8 global traffic
  constexpr int CPR = BN / 8;  // 16B chunks per row
#pragma unroll
  for (int c = tid; c < BM * CPR; c += 256) {
    const int row = c / CPR;
    const int off8 = (c % CPR) * 8;
    const int row_g = bm + row;
    half8 hv = *(const half8*)(Cs + row * BN + off8);
    if constexpr (EPI == 0) {  // x-part of cat, cat2
      *(half8*)(g.cat + (size_t)row_g * 1536 + 1024 + bn + off8) = hv;
      *(half8*)(g.cat2 + (size_t)row_g * 1536 + 1024 + bn + off8) = hv;
    } else if constexpr (EPI == 2) {
      if (bn < 1024) {  // u
        *(half8*)(g.u_h + (size_t)row_g * 1024 + bn + off8) = hv;
      } else {  // cat2 state-part = r * s'
        const int cc = bn - 1024 + off8;
        half8 sp = *(const half8*)(g.cat + (size_t)row_g * 1536 + cc);
        half8 o;
#pragma unroll
        for (int e = 0; e < 8; ++e) o[e] = (_Float16)((float)hv[e] * (float)sp[e]);
        *(half8*)(g.cat2 + (size_t)row_g * 1536 + cc) = o;
      }
    } else if constexpr (EPI == 3) {
      // hv = tanh(...); state = (1-u)s' + u*hv; s'_{t+1} = belta_{t+1}*state
      half8 sp = *(const half8*)(g.cat + (size_t)row_g * 1536 + bn + off8);
      half8 uu = *(const half8*)(g.u_h + (size_t)row_g * 1024 + bn + off8);
      half8 st;
#pragma unroll
      for (int e = 0; e < 8; ++e) {
        float u = (float)uu[e];
        st[e] = (_Float16)((1.f - u) * (float)sp[e] + u * (float)hv[e]);
      }
      *(half8*)(g.state_h + (size_t)row_g * 1024 + bn + off8) = st;
      if (g.t < 11) {
        half8 bl = *(const half8*)(g.belta + (size_t)g.t * 4194304 +
                                   (size_t)row_g * 1024 + bn + off8);
        half8 ns;
#pragma unroll
        for (int e = 0; e < 8; ++e)
          ns[e] = (_Float16)((float)bl[e] * (float)st[e]);
        *(half8*)(g.cat + (size_t)row_g * 1536 + bn + off8) = ns;
      }
    } else if constexpr (EPI == 4) {  // out (f32) + next x (f16)
      *(half8*)(g.cat + (size_t)row_g * 1536 + 1024 + bn + off8) = hv;
      *(half8*)(g.cat2 + (size_t)row_g * 1536 + 1024 + bn + off8) = hv;
      float* op = g.out + ((size_t)row_g * 12 + g.t) * 512 + bn + off8;
      float4 f0, f1;
      f0.x = (float)hv[0]; f0.y = (float)hv[1];
      f0.z = (float)hv[2]; f0.w = (float)hv[3];
      f1.x = (float)hv[4]; f1.y = (float)hv[5];
      f1.z = (float)hv[6]; f1.w = (float)hv[7];
      *(float4*)op = f0;
      *(float4*)(op + 4) = f1;
    } else {  // EPI 5: belta rows are tm*128 + row
      *(half8*)(g.belta + (size_t)row_g * 1024 + bn + off8) = hv;
    }
  }
}

// f32 [K][N] row-major -> f16 [N][K] (transposed) via 32x32 LDS tile
__global__ __launch_bounds__(256) void transpose_cvt(const float* __restrict__ src,
                                                     _Float16* __restrict__ dst,
                                                     int K, int N) {
  __shared__ float tile[32][33];
  const int nb = blockIdx.x * 32;
  const int kb = blockIdx.y * 32;
  const int tx = threadIdx.x & 31;
  const int ty = threadIdx.x >> 5;
#pragma unroll
  for (int i = ty; i < 32; i += 8)
    tile[i][tx] = src[(size_t)(kb + i) * N + nb + tx];
  __syncthreads();
#pragma unroll
  for (int i = ty; i < 32; i += 8)
    dst[(size_t)(nb + i) * K + kb + tx] = (_Float16)tile[tx][i];
}

__global__ __launch_bounds__(256) void cvt_f16(const float* __restrict__ src,
                                               _Float16* __restrict__ dst) {
  size_t i = (size_t)blockIdx.x * blockDim.x + threadIdx.x;
  const float4* p = (const float4*)(src + i * 8);
  float4 a = p[0], b = p[1];
  half8 h;
  h[0] = (_Float16)a.x; h[1] = (_Float16)a.y;
  h[2] = (_Float16)a.z; h[3] = (_Float16)a.w;
  h[4] = (_Float16)b.x; h[5] = (_Float16)b.y;
  h[6] = (_Float16)b.z; h[7] = (_Float16)b.w;
  *(half8*)(dst + i * 8) = h;
}

__global__ __launch_bounds__(256) void zero_cat_state(_Float16* __restrict__ cat) {
  int i = blockIdx.x * blockDim.x + threadIdx.x;  // one half8 per thread
  int row = i >> 7;
  int c8 = (i & 127) << 3;
  half8 z = {(_Float16)0, (_Float16)0, (_Float16)0, (_Float16)0,
             (_Float16)0, (_Float16)0, (_Float16)0, (_Float16)0};
  *(half8*)(cat + (size_t)row * 1536 + c8) = z;
}

extern "C" void kernel_launch(void* const* d_in, const int* in_sizes, int n_in,
                              void* d_out, int out_size, void* d_ws,
                              size_t ws_size, hipStream_t stream) {
  const float* z  = (const float*)d_in[0];
  const float* td = (const float*)d_in[1];
  const float* Wb = (const float*)d_in[2];
  const float* bb = (const float*)d_in[3];
  const float* Wz = (const float*)d_in[4];
  const float* bz = (const float*)d_in[5];
  const float* W1 = (const float*)d_in[6];
  const float* b1 = (const float*)d_in[7];
  const float* W2 = (const float*)d_in[8];
  const float* b2 = (const float*)d_in[9];
  const float* W3 = (const float*)d_in[10];
  const float* b3 = (const float*)d_in[11];
  const float* Wo = (const float*)d_in[12];
  const float* bo = (const float*)d_in[13];
  float* out = (float*)d_out;

  char* ws = (char*)d_ws;
  size_t off = 0;
  auto alloc = [&](size_t bytes) {
    void* p = ws + off;
    off += (bytes + 255) & ~(size_t)255;
    return p;
  };
  _Float16* WzT  = (_Float16*)alloc((size_t)512 * 128 * 2);
  _Float16* WbT  = (_Float16*)alloc((size_t)1024 * 512 * 2);
  _Float16* W12T = (_Float16*)alloc((size_t)2048 * 1536 * 2);
  _Float16* W3T  = (_Float16*)alloc((size_t)1024 * 1536 * 2);
  _Float16* WoT  = (_Float16*)alloc((size_t)512 * 1024 * 2);
  _Float16* z_h  = (_Float16*)alloc((size_t)4096 * 128 * 2);
  _Float16* td_h = (_Float16*)alloc((size_t)4096 * 12 * 512 * 2);
  _Float16* cat  = (_Float16*)alloc((size_t)4096 * 1536 * 2);
  _Float16* cat2 = (_Float16*)alloc((size_t)4096 * 1536 * 2);
  _Float16* u_h  = (_Float16*)alloc((size_t)4096 * 1024 * 2);
  _Float16* st_h = (_Float16*)alloc((size_t)4096 * 1024 * 2);
  _Float16* beltaA = (_Float16*)alloc((size_t)11 * 4096 * 1024 * 2);
  if (off > ws_size) return;  // not enough scratch: fail cleanly

  dim3 blk(256);
  cvt_f16<<<12288, blk, 0, stream>>>(td, td_h);        // 4096*12*512
  transpose_cvt<<<dim3(16, 4), blk, 0, stream>>>(Wz, WzT, 128, 512);
  transpose_cvt<<<dim3(32, 16), blk, 0, stream>>>(Wb, WbT, 512, 1024);
  transpose_cvt<<<dim3(32, 48), blk, 0, stream>>>(W1, W12T, 1536, 1024);
  transpose_cvt<<<dim3(32, 48), blk, 0, stream>>>(W2, W12T + (size_t)1024 * 1536,
                                                  1536, 1024);
  transpose_cvt<<<dim3(32, 48), blk, 0, stream>>>(W3, W3T, 1536, 1024);
  transpose_cvt<<<dim3(16, 32), blk, 0, stream>>>(Wo, WoT, 1024, 512);
  cvt_f16<<<256, blk, 0, stream>>>(z, z_h);            // 4096*128
  zero_cat_state<<<2048, blk, 0, stream>>>(cat);       // cat[:, :1024] = 0

  {  // belta (t=1..11) in one parallel GEMM: M=45056, N=1024, K=512
    GArgs a{};
    a.A = td_h; a.BT = WbT; a.K = 512; a.bias = bb; a.belta = beltaA;
    a.XC = 1; a.RM = 44; a.RN = 8;   // tile grid 352 x 8
    gemm_k<5, 128, 128><<<2816, blk, 0, stream>>>(a);
  }
  {  // x = z @ Wz + bz
    GArgs a{};
    a.A = z_h; a.BT = WzT; a.lda = 128; a.K = 128;
    a.bias = bz; a.cat = cat; a.cat2 = cat2;
    a.XC = 2; a.RM = 8; a.RN = 4;    // tile grid 32 x 8
    gemm_k<0, 128, 64><<<256, blk, 0, stream>>>(a);
  }
  for (int t = 0; t < 12; ++t) {
    {  // [u | r] = sigmoid(cat @ [W1|W2] + [b1|b2]); cat2 state-part = r*s'
      GArgs a{};
      a.A = cat; a.BT = W12T; a.lda = 1536; a.K = 1536;
      a.bias = b1; a.bias2 = b2; a.u_h = u_h; a.cat = cat; a.cat2 = cat2;
      a.XC = 4; a.RM = 16; a.RN = 8;  // tile grid 32 x 32
      gemm_k<2, 128, 64><<<1024, blk, 0, stream>>>(a);
    }
    {  // state = (1-u)*s' + u*tanh(cat2 @ W3 + b3); s'_{t+1} = belta*state
      GArgs a{};
      a.A = cat2; a.BT = W3T; a.lda = 1536; a.K = 1536;
      a.bias = b3; a.cat = cat; a.u_h = u_h; a.state_h = st_h;
      a.belta = beltaA; a.t = t;
      a.XC = 2; a.RM = 8; a.RN = 8;  // tile grid 32 x 16
      gemm_k<3, 128, 64><<<512, blk, 0, stream>>>(a);
    }
    {  // out_t = state @ Wout + bo -> d_out[:, t, :], next x
      GArgs a{};
      a.A = st_h; a.BT = WoT; a.lda = 1024; a.K = 1024;
      a.bias = bo; a.cat = cat; a.cat2 = cat2; a.out = out; a.t = t;
      a.XC = 1; a.RM = 8; a.RN = 8;  // tile grid 64 x 8
      gemm_k<4, 64, 64><<<512, blk, 0, stream>>>(a);
    }
  }
}